// Round 1
// baseline (539.409 us; speedup 1.0000x reference)
//
#include <hip/hip_runtime.h>
#include <hip/hip_bf16.h>

#define BATCH 16
#define CH    128
#define NPIX  16384
#define NHEAD 8

typedef __attribute__((ext_vector_type(8))) short bf16x8;
typedef __attribute__((ext_vector_type(4))) float f32x4;

__device__ __forceinline__ short f2b(float f) {
    union { float f; unsigned u; } v; v.f = f;
    unsigned r = v.u + 0x7fffu + ((v.u >> 16) & 1u);   // RNE
    return (short)(r >> 16);
}

// ---------------------------------------------------------------------------
// k1: keys/values GEMM + exp + context accumulation.
// Block: 256 thr (4 waves), 256 positions (4 subtiles of 64). Grid: 16*64.
// Wave w owns out-channel rows 32w..32w+31 of Wk/Wv = heads 2w, 2w+1.
// GEMM as D[pos][kc]: A = x (row=pos=l&15, k=c), B = W^T (col=kc=l&15, k=c).
// S-GEMM: E,V both in D-layout -> shared k-bijection over positions, no xpose.
// ---------------------------------------------------------------------------
__global__ __launch_bounds__(256)
void k1_context(const float* __restrict__ x,
                const float* __restrict__ Wk, const float* __restrict__ bk,
                const float* __restrict__ Wv, const float* __restrict__ bv,
                float* __restrict__ Sg, float* __restrict__ Zg)
{
    const int tid  = threadIdx.x;
    const int w    = tid >> 6;
    const int lane = tid & 63;
    const int lo   = lane & 15;
    const int hi   = lane >> 4;

    const int b     = blockIdx.x >> 6;
    const int chunk = blockIdx.x & 63;
    const size_t xbase = (size_t)b * CH * NPIX;

    // Persistent weight fragments: W[row = 32w+ct*16+lo][c = ks*32+hi*8+j]
    bf16x8 wkf[2][4], wvf[2][4];
    #pragma unroll
    for (int ct = 0; ct < 2; ++ct) {
        const int row = 32*w + ct*16 + lo;
        #pragma unroll
        for (int ks = 0; ks < 4; ++ks) {
            const int c0 = ks*32 + hi*8;
            const float* pk = Wk + row*CH + c0;
            const float* pv = Wv + row*CH + c0;
            bf16x8 fk, fv;
            #pragma unroll
            for (int j = 0; j < 8; ++j) { fk[j] = f2b(pk[j]); fv[j] = f2b(pv[j]); }
            wkf[ct][ks] = fk; wvf[ct][ks] = fv;
        }
    }
    float bkv[2], bvv[2];
    #pragma unroll
    for (int ct = 0; ct < 2; ++ct) {
        bkv[ct] = bk[32*w + ct*16 + lo];
        bvv[ct] = bv[32*w + ct*16 + lo];
    }

    const f32x4 zero4 = {0.f, 0.f, 0.f, 0.f};
    f32x4 sacc[2] = {zero4, zero4};   // S[kc=hi*4+r][vc=lo] per owned head
    float zacc[2] = {0.f, 0.f};       // Z partial for kc = 32w+ct*16+lo

    for (int sub = 0; sub < 4; ++sub) {
        const int p0 = chunk*256 + sub*64;
        f32x4 dk_[2][4], dv_[2][4];   // [ct][pos-tile]
        #pragma unroll
        for (int ct = 0; ct < 2; ++ct)
            #pragma unroll
            for (int pt = 0; pt < 4; ++pt) { dk_[ct][pt] = zero4; dv_[ct][pt] = zero4; }

        #pragma unroll
        for (int ks = 0; ks < 4; ++ks) {
            bf16x8 xa[4];
            #pragma unroll
            for (int pt = 0; pt < 4; ++pt) {
                // lane: pos = p0+pt*16+lo, c = ks*32+hi*8+j  (16-lane groups read
                // 64B contiguous segments per j -> coalesced)
                const float* px = x + xbase + (size_t)(ks*32 + hi*8) * NPIX
                                + (size_t)(p0 + pt*16 + lo);
                bf16x8 f;
                #pragma unroll
                for (int j = 0; j < 8; ++j) f[j] = f2b(px[(size_t)j * NPIX]);
                xa[pt] = f;
            }
            #pragma unroll
            for (int ct = 0; ct < 2; ++ct)
                #pragma unroll
                for (int pt = 0; pt < 4; ++pt) {
                    dk_[ct][pt] = __builtin_amdgcn_mfma_f32_16x16x32_bf16(xa[pt], wkf[ct][ks], dk_[ct][pt], 0, 0, 0);
                    dv_[ct][pt] = __builtin_amdgcn_mfma_f32_16x16x32_bf16(xa[pt], wvf[ct][ks], dv_[ct][pt], 0, 0, 0);
                }
        }

        // exp + Z + pack E,V (both in D-layout: kc=lo, pos=hi*4+r per pt)
        // k-bijection for the S-mfma: jj=(pt&1)*4+r  ->  pos = pt*16+hi*4+r.
        #pragma unroll
        for (int ct = 0; ct < 2; ++ct) {
            bf16x8 ef[2], vf[2];
            #pragma unroll
            for (int pt = 0; pt < 4; ++pt) {
                #pragma unroll
                for (int r = 0; r < 4; ++r) {
                    float e = __expf(dk_[ct][pt][r] + bkv[ct]);
                    zacc[ct] += e;
                    ef[pt >> 1][(pt & 1)*4 + r] = f2b(e);
                    vf[pt >> 1][(pt & 1)*4 + r] = f2b(dv_[ct][pt][r] + bvv[ct]);
                }
            }
            #pragma unroll
            for (int kg = 0; kg < 2; ++kg)
                sacc[ct] = __builtin_amdgcn_mfma_f32_16x16x32_bf16(ef[kg], vf[kg], sacc[ct], 0, 0, 0);
        }
    }

    #pragma unroll
    for (int ct = 0; ct < 2; ++ct) {
        float z = zacc[ct];
        z += __shfl_xor(z, 16, 64);
        z += __shfl_xor(z, 32, 64);
        if (hi == 0)
            atomicAdd(&Zg[b*CH + 32*w + ct*16 + lo], z);
        float* sp = Sg + (size_t)(b*NHEAD + 2*w + ct) * 256;
        #pragma unroll
        for (int r = 0; r < 4; ++r)
            atomicAdd(&sp[(hi*4 + r)*16 + lo], sacc[ct][r]);
    }
}

// ---------------------------------------------------------------------------
// k1.5: Meff[b][c][16h+kc] = sum_vc Wr[c][16h+vc] * S[b][h][kc][vc] / Z[b][16h+kc]
// ---------------------------------------------------------------------------
__global__ __launch_bounds__(256)
void k15_meff(const float* __restrict__ Sg, const float* __restrict__ Zg,
              const float* __restrict__ Wr, float* __restrict__ Meff)
{
    const int b   = blockIdx.x >> 6;
    const int idx = (blockIdx.x & 63) * 256 + threadIdx.x;  // 0..16383
    const int c   = idx >> 7;
    const int kcg = idx & 127;
    const int h   = kcg >> 4;
    const int kc  = kcg & 15;
    const float* sp = Sg + ((size_t)(b*NHEAD + h) * 16 + kc) * 16;
    const float* wr = Wr + (size_t)c * CH + h*16;
    float acc = 0.f;
    #pragma unroll
    for (int v = 0; v < 16; ++v) acc += wr[v] * sp[v];
    Meff[((size_t)b*CH + c)*CH + kcg] = acc / Zg[b*CH + kcg];
}

// ---------------------------------------------------------------------------
// k2: Q GEMM -> per-head softmax (shfl over the 16 lanes holding one head)
//     -> swizzled LDS transpose of q -> out GEMM with Meff -> +br +x.
// ---------------------------------------------------------------------------
__global__ __launch_bounds__(256)
void k2_out(const float* __restrict__ x,
            const float* __restrict__ Wq, const float* __restrict__ bq,
            const float* __restrict__ Meff, const float* __restrict__ br,
            float* __restrict__ out)
{
    __shared__ __align__(16) short qlds[64 * 128];   // [pos][kc] bf16, XOR-swizzled

    const int tid  = threadIdx.x;
    const int w    = tid >> 6;
    const int lane = tid & 63;
    const int lo   = lane & 15;
    const int hi   = lane >> 4;

    const int b     = blockIdx.x >> 6;
    const int chunk = blockIdx.x & 63;
    const size_t xbase = (size_t)b * CH * NPIX;

    bf16x8 wqf[2][4], mf[2][4];
    #pragma unroll
    for (int ct = 0; ct < 2; ++ct) {
        const int row = 32*w + ct*16 + lo;
        #pragma unroll
        for (int ks = 0; ks < 4; ++ks) {
            const int c0 = ks*32 + hi*8;
            const float* pq = Wq + row*CH + c0;
            const float* pm = Meff + ((size_t)b*CH + row)*CH + c0;
            bf16x8 fq, fm;
            #pragma unroll
            for (int j = 0; j < 8; ++j) { fq[j] = f2b(pq[j]); fm[j] = f2b(pm[j]); }
            wqf[ct][ks] = fq; mf[ct][ks] = fm;
        }
    }
    float bqv[2];
    #pragma unroll
    for (int ct = 0; ct < 2; ++ct) bqv[ct] = bq[32*w + ct*16 + lo];
    float brv[2][4];
    #pragma unroll
    for (int ct = 0; ct < 2; ++ct)
        #pragma unroll
        for (int r = 0; r < 4; ++r) brv[ct][r] = br[32*w + ct*16 + hi*4 + r];

    const f32x4 zero4 = {0.f, 0.f, 0.f, 0.f};

    for (int sub = 0; sub < 4; ++sub) {
        const int p0 = chunk*256 + sub*64;

        // --- stage A: queries D[pos][qc] ---
        f32x4 dq[2][4];
        #pragma unroll
        for (int ct = 0; ct < 2; ++ct)
            #pragma unroll
            for (int pt = 0; pt < 4; ++pt) dq[ct][pt] = zero4;

        #pragma unroll
        for (int ks = 0; ks < 4; ++ks) {
            bf16x8 xa[4];
            #pragma unroll
            for (int pt = 0; pt < 4; ++pt) {
                const float* px = x + xbase + (size_t)(ks*32 + hi*8) * NPIX
                                + (size_t)(p0 + pt*16 + lo);
                bf16x8 f;
                #pragma unroll
                for (int j = 0; j < 8; ++j) f[j] = f2b(px[(size_t)j * NPIX]);
                xa[pt] = f;
            }
            #pragma unroll
            for (int ct = 0; ct < 2; ++ct)
                #pragma unroll
                for (int pt = 0; pt < 4; ++pt)
                    dq[ct][pt] = __builtin_amdgcn_mfma_f32_16x16x32_bf16(xa[pt], wqf[ct][ks], dq[ct][pt], 0, 0, 0);
        }

        // --- stage B: softmax over the head's 16 channels (lanes lo 0..15) ---
        #pragma unroll
        for (int ct = 0; ct < 2; ++ct) {
            const int qc = 32*w + ct*16 + lo;
            #pragma unroll
            for (int pt = 0; pt < 4; ++pt) {
                #pragma unroll
                for (int r = 0; r < 4; ++r) {
                    float v = dq[ct][pt][r] + bqv[ct];
                    float m = v;
                    m = fmaxf(m, __shfl_xor(m, 1, 64));
                    m = fmaxf(m, __shfl_xor(m, 2, 64));
                    m = fmaxf(m, __shfl_xor(m, 4, 64));
                    m = fmaxf(m, __shfl_xor(m, 8, 64));
                    float e = __expf(v - m);
                    float s = e;
                    s += __shfl_xor(s, 1, 64);
                    s += __shfl_xor(s, 2, 64);
                    s += __shfl_xor(s, 4, 64);
                    s += __shfl_xor(s, 8, 64);
                    const float q = e / s;
                    const int pos = pt*16 + hi*4 + r;
                    const int sidx = (pos*128 + qc) ^ ((pos & 7) << 3);
                    qlds[sidx] = f2b(q);
                }
            }
        }
        __syncthreads();

        // --- stage C: out D[c][pos] = Meff · q ---
        f32x4 d2[2][4];
        #pragma unroll
        for (int ct = 0; ct < 2; ++ct)
            #pragma unroll
            for (int pt = 0; pt < 4; ++pt) d2[ct][pt] = zero4;

        #pragma unroll
        for (int ks = 0; ks < 4; ++ks) {
            bf16x8 qf[4];
            #pragma unroll
            for (int pt = 0; pt < 4; ++pt) {
                const int pos  = pt*16 + lo;
                const int sidx = (pos*128 + ks*32 + hi*8) ^ ((pos & 7) << 3);
                qf[pt] = *(const bf16x8*)&qlds[sidx];
            }
            #pragma unroll
            for (int ct = 0; ct < 2; ++ct)
                #pragma unroll
                for (int pt = 0; pt < 4; ++pt)
                    d2[ct][pt] = __builtin_amdgcn_mfma_f32_16x16x32_bf16(mf[ct][ks], qf[pt], d2[ct][pt], 0, 0, 0);
        }

        // --- epilogue: + br + x, store ---
        #pragma unroll
        for (int ct = 0; ct < 2; ++ct)
            #pragma unroll
            for (int pt = 0; pt < 4; ++pt) {
                const int n = p0 + pt*16 + lo;
                #pragma unroll
                for (int r = 0; r < 4; ++r) {
                    const int cc = 32*w + ct*16 + hi*4 + r;
                    const size_t o = xbase + (size_t)cc * NPIX + n;
                    out[o] = d2[ct][pt][r] + brv[ct][r] + x[o];
                }
            }
        __syncthreads();
    }
}

extern "C" void kernel_launch(void* const* d_in, const int* in_sizes, int n_in,
                              void* d_out, int out_size, void* d_ws, size_t ws_size,
                              hipStream_t stream)
{
    const float* x  = (const float*)d_in[0];
    const float* Wk = (const float*)d_in[1];
    const float* bk = (const float*)d_in[2];
    const float* Wq = (const float*)d_in[3];
    const float* bq = (const float*)d_in[4];
    const float* Wv = (const float*)d_in[5];
    const float* bv = (const float*)d_in[6];
    const float* Wr = (const float*)d_in[7];
    const float* br = (const float*)d_in[8];
    float* out = (float*)d_out;

    float* Sg   = (float*)d_ws;        // 16*8*16*16 = 32768 floats
    float* Zg   = Sg + 32768;          // 16*128     = 2048 floats
    float* Meff = Zg + 2048;           // 16*128*128 = 262144 floats

    hipMemsetAsync(d_ws, 0, (32768 + 2048) * sizeof(float), stream);

    k1_context<<<dim3(BATCH * 64), dim3(256), 0, stream>>>(x, Wk, bk, Wv, bv, Sg, Zg);
    k15_meff  <<<dim3(BATCH * 64), dim3(256), 0, stream>>>(Sg, Zg, Wr, Meff);
    k2_out    <<<dim3(BATCH * 64), dim3(256), 0, stream>>>(x, Wq, bq, Meff, br, out);
}

// Round 3
// 442.913 us; speedup vs baseline: 1.2179x; 1.2179x over previous
//
#include <hip/hip_runtime.h>
#include <hip/hip_bf16.h>

#define BATCH 16
#define CH    128
#define NPIX  16384
#define NHEAD 8

typedef __attribute__((ext_vector_type(8))) short bf16x8;
typedef __attribute__((ext_vector_type(4))) float f32x4;

__device__ __forceinline__ short f2b(float f) {
    union { float f; unsigned u; } v; v.f = f;
    unsigned r = v.u + 0x7fffu + ((v.u >> 16) & 1u);   // RNE
    return (short)(r >> 16);
}

// Element-index swizzle for the x tile: LDS layout [pos][ch] bf16.
// v(p) = ((p>>2)&15) ^ ((p&3)<<2); XOR (v<<3) into the channel bits.
// - staging writes (thread owns p = 4L+kk, c fixed): banks spread by L -> conflict-free
// - fragment reads (lane lo = pos&15, 8ch b128): 8 slices x 8 lanes -> baseline
__device__ __forceinline__ int xswz(int p, int c) {
    const int v = ((p >> 2) & 15) ^ ((p & 3) << 2);
    return (p * CH + c) ^ (v << 3);
}

// Stage x[b][0..127][p0..p0+63] (fp32, pos-contiguous) -> lds [pos][ch] bf16.
__device__ __forceinline__ void stage_x(const float* __restrict__ xb, int p0,
                                        ushort* lds, int tid) {
    #pragma unroll
    for (int i = 0; i < 8; ++i) {
        const int idx = tid + i * 256;            // 0..2047
        const int c   = idx >> 4;                 // 0..127
        const int L   = idx & 15;                 // float4 column
        const float4 v4 = *(const float4*)(xb + (size_t)c * NPIX + p0 + L * 4);
        #pragma unroll
        for (int kk = 0; kk < 4; ++kk) {
            const int p = L * 4 + kk;
            lds[xswz(p, c)] = (ushort)f2b(((const float*)&v4)[kk]);
        }
    }
}

// ---------------------------------------------------------------------------
// k1: keys/values GEMM + exp + context accumulation. 256 thr, 256 pos/block.
// ---------------------------------------------------------------------------
__global__ __launch_bounds__(256)
void k1_context(const float* __restrict__ x,
                const float* __restrict__ Wk, const float* __restrict__ bk,
                const float* __restrict__ Wv, const float* __restrict__ bv,
                float* __restrict__ Sg, float* __restrict__ Zg)
{
    __shared__ __align__(16) ushort xlds[64 * CH];   // 16 KB

    const int tid  = threadIdx.x;
    const int w    = tid >> 6;
    const int lane = tid & 63;
    const int lo   = lane & 15;
    const int hi   = lane >> 4;

    const int b     = blockIdx.x >> 6;
    const int chunk = blockIdx.x & 63;
    const float* xb = x + (size_t)b * CH * NPIX;

    // Weight fragments: W[row = 32w+ct*16+lo][c = ks*32+hi*8+j]
    bf16x8 wkf[2][4], wvf[2][4];
    #pragma unroll
    for (int ct = 0; ct < 2; ++ct) {
        const int row = 32*w + ct*16 + lo;
        #pragma unroll
        for (int ks = 0; ks < 4; ++ks) {
            const int c0 = ks*32 + hi*8;
            const float* pk = Wk + row*CH + c0;
            const float* pv = Wv + row*CH + c0;
            bf16x8 fk, fv;
            #pragma unroll
            for (int j = 0; j < 8; ++j) { fk[j] = f2b(pk[j]); fv[j] = f2b(pv[j]); }
            wkf[ct][ks] = fk; wvf[ct][ks] = fv;
        }
    }
    float bkv[2], bvv[2];
    #pragma unroll
    for (int ct = 0; ct < 2; ++ct) {
        bkv[ct] = bk[32*w + ct*16 + lo];
        bvv[ct] = bv[32*w + ct*16 + lo];
    }

    const f32x4 zero4 = {0.f, 0.f, 0.f, 0.f};
    f32x4 sacc[2] = {zero4, zero4};
    float zacc[2] = {0.f, 0.f};

    for (int sub = 0; sub < 4; ++sub) {
        const int p0 = chunk*256 + sub*64;
        __syncthreads();                       // previous sub's readers done
        stage_x(xb, p0, xlds, tid);
        __syncthreads();

        f32x4 dk_[2][4], dv_[2][4];
        #pragma unroll
        for (int ct = 0; ct < 2; ++ct)
            #pragma unroll
            for (int pt = 0; pt < 4; ++pt) { dk_[ct][pt] = zero4; dv_[ct][pt] = zero4; }

        #pragma unroll
        for (int ks = 0; ks < 4; ++ks) {
            #pragma unroll
            for (int pt = 0; pt < 4; ++pt) {
                const bf16x8 xa = *(const bf16x8*)&xlds[xswz(pt*16 + lo, ks*32 + hi*8)];
                #pragma unroll
                for (int ct = 0; ct < 2; ++ct) {
                    dk_[ct][pt] = __builtin_amdgcn_mfma_f32_16x16x32_bf16(xa, wkf[ct][ks], dk_[ct][pt], 0, 0, 0);
                    dv_[ct][pt] = __builtin_amdgcn_mfma_f32_16x16x32_bf16(xa, wvf[ct][ks], dv_[ct][pt], 0, 0, 0);
                }
            }
        }

        // exp + Z + pack E,V (D-layout both sides -> shared k-bijection)
        #pragma unroll
        for (int ct = 0; ct < 2; ++ct) {
            bf16x8 ef[2], vf[2];
            #pragma unroll
            for (int pt = 0; pt < 4; ++pt) {
                #pragma unroll
                for (int r = 0; r < 4; ++r) {
                    float e = __expf(dk_[ct][pt][r] + bkv[ct]);
                    zacc[ct] += e;
                    ef[pt >> 1][(pt & 1)*4 + r] = f2b(e);
                    vf[pt >> 1][(pt & 1)*4 + r] = f2b(dv_[ct][pt][r] + bvv[ct]);
                }
            }
            #pragma unroll
            for (int kg = 0; kg < 2; ++kg)
                sacc[ct] = __builtin_amdgcn_mfma_f32_16x16x32_bf16(ef[kg], vf[kg], sacc[ct], 0, 0, 0);
        }
    }

    #pragma unroll
    for (int ct = 0; ct < 2; ++ct) {
        float z = zacc[ct];
        z += __shfl_xor(z, 16, 64);
        z += __shfl_xor(z, 32, 64);
        if (hi == 0)
            atomicAdd(&Zg[b*CH + 32*w + ct*16 + lo], z);
        float* sp = Sg + (size_t)(b*NHEAD + 2*w + ct) * 256;
        #pragma unroll
        for (int r = 0; r < 4; ++r)
            atomicAdd(&sp[(hi*4 + r)*16 + lo], sacc[ct][r]);
    }
}

// ---------------------------------------------------------------------------
// k1.5: Meff[b][c][16h+kc] = sum_vc Wr[c][16h+vc] * S[b][h][kc][vc] / Z[b][16h+kc]
// ---------------------------------------------------------------------------
__global__ __launch_bounds__(256)
void k15_meff(const float* __restrict__ Sg, const float* __restrict__ Zg,
              const float* __restrict__ Wr, float* __restrict__ Meff)
{
    const int b   = blockIdx.x >> 6;
    const int idx = (blockIdx.x & 63) * 256 + threadIdx.x;
    const int c   = idx >> 7;
    const int kcg = idx & 127;
    const int h   = kcg >> 4;
    const int kc  = kcg & 15;
    const float* sp = Sg + ((size_t)(b*NHEAD + h) * 16 + kc) * 16;
    const float* wr = Wr + (size_t)c * CH + h*16;
    float acc = 0.f;
    #pragma unroll
    for (int v = 0; v < 16; ++v) acc += wr[v] * sp[v];
    Meff[((size_t)b*CH + c)*CH + kcg] = acc / Zg[b*CH + kcg];
}

// ---------------------------------------------------------------------------
// k2: Q GEMM -> per-head softmax (no max-sub; logits bounded) -> q transpose
//     via qlds -> out GEMM with Meff -> + br + x(residual from LDS tile).
// ---------------------------------------------------------------------------
__global__ __launch_bounds__(256)
void k2_out(const float* __restrict__ x,
            const float* __restrict__ Wq, const float* __restrict__ bq,
            const float* __restrict__ Meff, const float* __restrict__ br,
            float* __restrict__ out)
{
    __shared__ __align__(16) ushort xlds[64 * CH];   // 16 KB
    __shared__ __align__(16) ushort qlds[64 * CH];   // 16 KB

    const int tid  = threadIdx.x;
    const int w    = tid >> 6;
    const int lane = tid & 63;
    const int lo   = lane & 15;
    const int hi   = lane >> 4;

    const int b     = blockIdx.x >> 6;
    const int chunk = blockIdx.x & 63;
    const size_t xbase = (size_t)b * CH * NPIX;
    const float* xb = x + xbase;

    bf16x8 wqf[2][4], mf[2][4];
    #pragma unroll
    for (int ct = 0; ct < 2; ++ct) {
        const int row = 32*w + ct*16 + lo;
        #pragma unroll
        for (int ks = 0; ks < 4; ++ks) {
            const int c0 = ks*32 + hi*8;
            const float* pq = Wq + row*CH + c0;
            const float* pm = Meff + ((size_t)b*CH + row)*CH + c0;
            bf16x8 fq, fm;
            #pragma unroll
            for (int j = 0; j < 8; ++j) { fq[j] = f2b(pq[j]); fm[j] = f2b(pm[j]); }
            wqf[ct][ks] = fq; mf[ct][ks] = fm;
        }
    }
    float bqv[2];
    #pragma unroll
    for (int ct = 0; ct < 2; ++ct) bqv[ct] = bq[32*w + ct*16 + lo];
    float brv[2][4];
    #pragma unroll
    for (int ct = 0; ct < 2; ++ct)
        #pragma unroll
        for (int r = 0; r < 4; ++r) brv[ct][r] = br[32*w + ct*16 + hi*4 + r];

    const f32x4 zero4 = {0.f, 0.f, 0.f, 0.f};

    for (int sub = 0; sub < 4; ++sub) {
        const int p0 = chunk*256 + sub*64;
        __syncthreads();                       // previous sub's readers done
        stage_x(xb, p0, xlds, tid);
        __syncthreads();

        // --- stage A: queries D[pos][qc] ---
        f32x4 dq[2][4];
        #pragma unroll
        for (int ct = 0; ct < 2; ++ct)
            #pragma unroll
            for (int pt = 0; pt < 4; ++pt) dq[ct][pt] = zero4;

        #pragma unroll
        for (int ks = 0; ks < 4; ++ks) {
            #pragma unroll
            for (int pt = 0; pt < 4; ++pt) {
                const bf16x8 xa = *(const bf16x8*)&xlds[xswz(pt*16 + lo, ks*32 + hi*8)];
                #pragma unroll
                for (int ct = 0; ct < 2; ++ct)
                    dq[ct][pt] = __builtin_amdgcn_mfma_f32_16x16x32_bf16(xa, wqf[ct][ks], dq[ct][pt], 0, 0, 0);
            }
        }

        // --- stage B: softmax over head channels (16 lanes), no max-sub ---
        #pragma unroll
        for (int ct = 0; ct < 2; ++ct) {
            const int qc = 32*w + ct*16 + lo;
            #pragma unroll
            for (int pt = 0; pt < 4; ++pt) {
                #pragma unroll
                for (int r = 0; r < 4; ++r) {
                    const float e = __expf(dq[ct][pt][r] + bqv[ct]);
                    float s = e;
                    s += __shfl_xor(s, 1, 64);
                    s += __shfl_xor(s, 2, 64);
                    s += __shfl_xor(s, 4, 64);
                    s += __shfl_xor(s, 8, 64);
                    const float q = e / s;
                    const int pos = pt*16 + hi*4 + r;
                    const int sidx = (pos*CH + qc) ^ ((pos & 7) << 3);
                    qlds[sidx] = (ushort)f2b(q);
                }
            }
        }
        __syncthreads();

        // --- stage C: out D[c][pos] = Meff · q ---
        f32x4 d2[2][4];
        #pragma unroll
        for (int ct = 0; ct < 2; ++ct)
            #pragma unroll
            for (int pt = 0; pt < 4; ++pt) d2[ct][pt] = zero4;

        #pragma unroll
        for (int ks = 0; ks < 4; ++ks) {
            #pragma unroll
            for (int pt = 0; pt < 4; ++pt) {
                const int pos  = pt*16 + lo;
                const int sidx = (pos*CH + ks*32 + hi*8) ^ ((pos & 7) << 3);
                const bf16x8 qf = *(const bf16x8*)&qlds[sidx];
                #pragma unroll
                for (int ct = 0; ct < 2; ++ct)
                    d2[ct][pt] = __builtin_amdgcn_mfma_f32_16x16x32_bf16(mf[ct][ks], qf, d2[ct][pt], 0, 0, 0);
            }
        }

        // --- epilogue: + br + x (residual from LDS tile, bf16) ---
        #pragma unroll
        for (int ct = 0; ct < 2; ++ct)
            #pragma unroll
            for (int pt = 0; pt < 4; ++pt) {
                const int n   = p0 + pt*16 + lo;
                const int pos = pt*16 + lo;
                #pragma unroll
                for (int r = 0; r < 4; ++r) {
                    const int cc = 32*w + ct*16 + hi*4 + r;
                    union { unsigned u; float f; } xr;
                    xr.u = ((unsigned)xlds[xswz(pos, cc)]) << 16;
                    out[xbase + (size_t)cc * NPIX + n] = d2[ct][pt][r] + brv[ct][r] + xr.f;
                }
            }
    }
}

extern "C" void kernel_launch(void* const* d_in, const int* in_sizes, int n_in,
                              void* d_out, int out_size, void* d_ws, size_t ws_size,
                              hipStream_t stream)
{
    const float* x  = (const float*)d_in[0];
    const float* Wk = (const float*)d_in[1];
    const float* bk = (const float*)d_in[2];
    const float* Wq = (const float*)d_in[3];
    const float* bq = (const float*)d_in[4];
    const float* Wv = (const float*)d_in[5];
    const float* bv = (const float*)d_in[6];
    const float* Wr = (const float*)d_in[7];
    const float* br = (const float*)d_in[8];
    float* out = (float*)d_out;

    float* Sg   = (float*)d_ws;        // 16*8*16*16 = 32768 floats
    float* Zg   = Sg + 32768;          // 16*128     = 2048 floats
    float* Meff = Zg + 2048;           // 16*128*128 = 262144 floats

    hipMemsetAsync(d_ws, 0, (32768 + 2048) * sizeof(float), stream);

    k1_context<<<dim3(BATCH * 64), dim3(256), 0, stream>>>(x, Wk, bk, Wv, bv, Sg, Zg);
    k15_meff  <<<dim3(BATCH * 64), dim3(256), 0, stream>>>(Sg, Zg, Wr, Meff);
    k2_out    <<<dim3(BATCH * 64), dim3(256), 0, stream>>>(x, Wq, bq, Meff, br, out);
}

// Round 4
// 436.148 us; speedup vs baseline: 1.2368x; 1.0155x over previous
//
#include <hip/hip_runtime.h>
#include <hip/hip_bf16.h>

#define BATCH 16
#define CH    128
#define NPIX  16384
#define NHEAD 8

typedef __attribute__((ext_vector_type(8))) short bf16x8;
typedef __attribute__((ext_vector_type(4))) float f32x4;

__device__ __forceinline__ short f2b(float f) {
    union { float f; unsigned u; } v; v.f = f;
    unsigned r = v.u + 0x7fffu + ((v.u >> 16) & 1u);   // RNE
    return (short)(r >> 16);
}
__device__ __forceinline__ float b2f(ushort u) {
    union { unsigned u; float f; } v; v.u = ((unsigned)u) << 16; return v.f;
}

// x tile swizzle: LDS [pos][ch] bf16; conflict-derived in R1 (verified passing).
__device__ __forceinline__ int xswz(int p, int c) {
    const int v = ((p >> 2) & 15) ^ ((p & 3) << 2);
    return (p * CH + c) ^ (v << 3);
}

// ---------------------------------------------------------------------------
// k1: K/V GEMM + exp + per-chunk context partials (NO atomics).
// grid 16*64, 256 thr. Register-prefetched x staging.
// ---------------------------------------------------------------------------
__global__ __launch_bounds__(256)
void k1_context(const float* __restrict__ x,
                const float* __restrict__ Wk, const float* __restrict__ bk,
                const float* __restrict__ Wv, const float* __restrict__ bv,
                float* __restrict__ Sp, float* __restrict__ Zp)
{
    __shared__ __align__(16) ushort xlds[64 * CH];   // 16 KB

    const int tid  = threadIdx.x;
    const int w    = tid >> 6;
    const int lane = tid & 63;
    const int lo   = lane & 15;
    const int hi   = lane >> 4;

    const int b     = blockIdx.x >> 6;
    const int chunk = blockIdx.x & 63;
    const float* xb = x + (size_t)b * CH * NPIX;

    const int pc = tid >> 4;        // staging channel base 0..15
    const int pL = tid & 15;        // staging float4 column

    // prefetch sub 0
    float4 pf[8];
    {
        const int p0 = chunk * 256;
        #pragma unroll
        for (int i = 0; i < 8; ++i)
            pf[i] = *(const float4*)(xb + (size_t)(pc + 16*i) * NPIX + p0 + pL * 4);
    }

    // weight fragments, vectorized loads
    bf16x8 wkf[2][4], wvf[2][4];
    #pragma unroll
    for (int ct = 0; ct < 2; ++ct) {
        const int row = 32*w + ct*16 + lo;
        #pragma unroll
        for (int ks = 0; ks < 4; ++ks) {
            const int c0 = ks*32 + hi*8;
            const float4 k0 = *(const float4*)(Wk + row*CH + c0);
            const float4 k1 = *(const float4*)(Wk + row*CH + c0 + 4);
            const float4 v0 = *(const float4*)(Wv + row*CH + c0);
            const float4 v1 = *(const float4*)(Wv + row*CH + c0 + 4);
            bf16x8 fk, fv;
            fk[0]=f2b(k0.x); fk[1]=f2b(k0.y); fk[2]=f2b(k0.z); fk[3]=f2b(k0.w);
            fk[4]=f2b(k1.x); fk[5]=f2b(k1.y); fk[6]=f2b(k1.z); fk[7]=f2b(k1.w);
            fv[0]=f2b(v0.x); fv[1]=f2b(v0.y); fv[2]=f2b(v0.z); fv[3]=f2b(v0.w);
            fv[4]=f2b(v1.x); fv[5]=f2b(v1.y); fv[6]=f2b(v1.z); fv[7]=f2b(v1.w);
            wkf[ct][ks] = fk; wvf[ct][ks] = fv;
        }
    }
    float bkv[2], bvv[2];
    #pragma unroll
    for (int ct = 0; ct < 2; ++ct) {
        bkv[ct] = bk[32*w + ct*16 + lo];
        bvv[ct] = bv[32*w + ct*16 + lo];
    }

    const f32x4 zero4 = {0.f, 0.f, 0.f, 0.f};
    f32x4 sacc[2] = {zero4, zero4};
    float zacc[2] = {0.f, 0.f};

    #pragma unroll
    for (int sub = 0; sub < 4; ++sub) {
        // commit prefetched regs -> LDS
        #pragma unroll
        for (int i = 0; i < 8; ++i) {
            const int c = pc + 16*i;
            #pragma unroll
            for (int kk = 0; kk < 4; ++kk)
                xlds[xswz(pL*4 + kk, c)] = (ushort)f2b(((const float*)&pf[i])[kk]);
        }
        __syncthreads();                                   // B1: xlds ready

        if (sub < 3) {                                     // prefetch next
            const int pn = chunk*256 + (sub+1)*64;
            #pragma unroll
            for (int i = 0; i < 8; ++i)
                pf[i] = *(const float4*)(xb + (size_t)(pc + 16*i) * NPIX + pn + pL * 4);
        }

        #pragma unroll
        for (int ct = 0; ct < 2; ++ct) {
            f32x4 dk_[4], dv_[4];
            #pragma unroll
            for (int pt = 0; pt < 4; ++pt) { dk_[pt] = zero4; dv_[pt] = zero4; }
            #pragma unroll
            for (int ks = 0; ks < 4; ++ks) {
                #pragma unroll
                for (int pt = 0; pt < 4; ++pt) {
                    const bf16x8 xa = *(const bf16x8*)&xlds[xswz(pt*16 + lo, ks*32 + hi*8)];
                    dk_[pt] = __builtin_amdgcn_mfma_f32_16x16x32_bf16(xa, wkf[ct][ks], dk_[pt], 0, 0, 0);
                    dv_[pt] = __builtin_amdgcn_mfma_f32_16x16x32_bf16(xa, wvf[ct][ks], dv_[pt], 0, 0, 0);
                }
            }
            bf16x8 ef[2], vf[2];
            #pragma unroll
            for (int pt = 0; pt < 4; ++pt) {
                #pragma unroll
                for (int r = 0; r < 4; ++r) {
                    float e = __expf(dk_[pt][r] + bkv[ct]);
                    zacc[ct] += e;
                    ef[pt >> 1][(pt & 1)*4 + r] = f2b(e);
                    vf[pt >> 1][(pt & 1)*4 + r] = f2b(dv_[pt][r] + bvv[ct]);
                }
            }
            #pragma unroll
            for (int kg = 0; kg < 2; ++kg)
                sacc[ct] = __builtin_amdgcn_mfma_f32_16x16x32_bf16(ef[kg], vf[kg], sacc[ct], 0, 0, 0);
        }
        __syncthreads();                                   // B2: xlds reads done
    }

    // store partials (plain coalesced stores, no atomics)
    float* sp = Sp + (size_t)(b*64 + chunk) * 2048;
    #pragma unroll
    for (int ct = 0; ct < 2; ++ct)
        #pragma unroll
        for (int r = 0; r < 4; ++r)
            sp[(2*w + ct)*256 + (hi*4 + r)*16 + lo] = sacc[ct][r];

    #pragma unroll
    for (int ct = 0; ct < 2; ++ct) {
        float z = zacc[ct];
        z += __shfl_xor(z, 16, 64);
        z += __shfl_xor(z, 32, 64);
        if (hi == 0)
            Zp[(size_t)(b*64 + chunk) * 128 + 32*w + ct*16 + lo] = z;
    }
}

// ---------------------------------------------------------------------------
// k1b: reduce per-chunk partials. grid (9,16), 256 thr.
// ---------------------------------------------------------------------------
__global__ __launch_bounds__(256)
void k1b_reduce(const float* __restrict__ Sp, const float* __restrict__ Zp,
                float* __restrict__ Sg, float* __restrict__ Zg)
{
    const int b = blockIdx.y;
    const int j = blockIdx.x * 256 + threadIdx.x;
    if (j < 2048) {
        const float* p = Sp + (size_t)b * 64 * 2048 + j;
        float a = 0.f;
        #pragma unroll 8
        for (int c = 0; c < 64; ++c) a += p[(size_t)c * 2048];
        Sg[b*2048 + j] = a;
    } else if (j < 2176) {
        const int k = j - 2048;
        const float* p = Zp + (size_t)b * 64 * 128 + k;
        float a = 0.f;
        #pragma unroll 8
        for (int c = 0; c < 64; ++c) a += p[(size_t)c * 128];
        Zg[b*128 + k] = a;
    }
}

// ---------------------------------------------------------------------------
// k15: Meff (bf16) = (Wr · S) / Z.  grid 16*64, 256 thr.
// ---------------------------------------------------------------------------
__global__ __launch_bounds__(256)
void k15_meff(const float* __restrict__ Sg, const float* __restrict__ Zg,
              const float* __restrict__ Wr, ushort* __restrict__ Meffh)
{
    const int b   = blockIdx.x >> 6;
    const int idx = (blockIdx.x & 63) * 256 + threadIdx.x;
    const int c   = idx >> 7;
    const int kcg = idx & 127;
    const int h   = kcg >> 4;
    const int kc  = kcg & 15;
    const float* sp = Sg + (size_t)b*2048 + h*256 + kc*16;
    const float* wr = Wr + (size_t)c * CH + h*16;
    float acc = 0.f;
    #pragma unroll
    for (int v4i = 0; v4i < 4; ++v4i) {
        const float4 sv = *(const float4*)(sp + v4i*4);
        const float4 wv = *(const float4*)(wr + v4i*4);
        acc += sv.x*wv.x + sv.y*wv.y + sv.z*wv.z + sv.w*wv.w;
    }
    Meffh[((size_t)b*CH + c)*CH + kcg] = (ushort)f2b(acc / Zg[b*128 + kcg]);
}

// ---------------------------------------------------------------------------
// k2: Q GEMM -> per-head softmax -> qlds transpose -> Meff GEMM ->
//     d2 transpose through ylds -> float4 residual+store. Prefetched staging.
// ---------------------------------------------------------------------------
__global__ __launch_bounds__(256)
void k2_out(const float* __restrict__ x,
            const float* __restrict__ Wq, const float* __restrict__ bq,
            const ushort* __restrict__ Meffh, const float* __restrict__ br,
            float* __restrict__ out)
{
    __shared__ __align__(16) ushort xlds[64 * CH];   // 16 KB
    __shared__ __align__(16) ushort qlds[64 * CH];   // 16 KB
    __shared__ __align__(16) ushort ylds[64 * CH];   // 16 KB  [c][pos] swizzled

    const int tid  = threadIdx.x;
    const int w    = tid >> 6;
    const int lane = tid & 63;
    const int lo   = lane & 15;
    const int hi   = lane >> 4;

    const int b     = blockIdx.x >> 6;
    const int chunk = blockIdx.x & 63;
    const size_t xbase = (size_t)b * CH * NPIX;
    const float* xb = x + xbase;
    float* outb = out + xbase;

    const int pc = tid >> 4;
    const int pL = tid & 15;

    // prefetch sub 0
    float4 pf[8];
    {
        const int p0 = chunk * 256;
        #pragma unroll
        for (int i = 0; i < 8; ++i)
            pf[i] = *(const float4*)(xb + (size_t)(pc + 16*i) * NPIX + p0 + pL * 4);
    }

    // weights: Wq fp32->bf16 fragments; Meff already bf16
    bf16x8 wqf[2][4], mf[2][4];
    #pragma unroll
    for (int ct = 0; ct < 2; ++ct) {
        const int row = 32*w + ct*16 + lo;
        #pragma unroll
        for (int ks = 0; ks < 4; ++ks) {
            const int c0 = ks*32 + hi*8;
            const float4 q0 = *(const float4*)(Wq + row*CH + c0);
            const float4 q1 = *(const float4*)(Wq + row*CH + c0 + 4);
            bf16x8 fq;
            fq[0]=f2b(q0.x); fq[1]=f2b(q0.y); fq[2]=f2b(q0.z); fq[3]=f2b(q0.w);
            fq[4]=f2b(q1.x); fq[5]=f2b(q1.y); fq[6]=f2b(q1.z); fq[7]=f2b(q1.w);
            wqf[ct][ks] = fq;
            mf[ct][ks] = *(const bf16x8*)(Meffh + ((size_t)b*CH + row)*CH + c0);
        }
    }
    float bqv[2];
    #pragma unroll
    for (int ct = 0; ct < 2; ++ct) bqv[ct] = bq[32*w + ct*16 + lo];
    float brv2[8];
    #pragma unroll
    for (int i = 0; i < 8; ++i) brv2[i] = br[pc + 16*i];

    const f32x4 zero4 = {0.f, 0.f, 0.f, 0.f};

    #pragma unroll
    for (int sub = 0; sub < 4; ++sub) {
        const int p0 = chunk*256 + sub*64;

        // commit prefetched regs -> xlds
        #pragma unroll
        for (int i = 0; i < 8; ++i) {
            const int c = pc + 16*i;
            #pragma unroll
            for (int kk = 0; kk < 4; ++kk)
                xlds[xswz(pL*4 + kk, c)] = (ushort)f2b(((const float*)&pf[i])[kk]);
        }
        __syncthreads();                                   // B1

        if (sub < 3) {
            const int pn = chunk*256 + (sub+1)*64;
            #pragma unroll
            for (int i = 0; i < 8; ++i)
                pf[i] = *(const float4*)(xb + (size_t)(pc + 16*i) * NPIX + pn + pL * 4);
        }

        // --- stage A: queries D[pos][qc] ---
        f32x4 dq[2][4];
        #pragma unroll
        for (int ct = 0; ct < 2; ++ct)
            #pragma unroll
            for (int pt = 0; pt < 4; ++pt) dq[ct][pt] = zero4;
        #pragma unroll
        for (int ks = 0; ks < 4; ++ks) {
            #pragma unroll
            for (int pt = 0; pt < 4; ++pt) {
                const bf16x8 xa = *(const bf16x8*)&xlds[xswz(pt*16 + lo, ks*32 + hi*8)];
                #pragma unroll
                for (int ct = 0; ct < 2; ++ct)
                    dq[ct][pt] = __builtin_amdgcn_mfma_f32_16x16x32_bf16(xa, wqf[ct][ks], dq[ct][pt], 0, 0, 0);
            }
        }

        // --- stage B: per-head softmax (16 lanes), write qlds ---
        #pragma unroll
        for (int ct = 0; ct < 2; ++ct) {
            const int qc = 32*w + ct*16 + lo;
            #pragma unroll
            for (int pt = 0; pt < 4; ++pt) {
                #pragma unroll
                for (int r = 0; r < 4; ++r) {
                    const float e = __expf(dq[ct][pt][r] + bqv[ct]);
                    float s = e;
                    s += __shfl_xor(s, 1, 64);
                    s += __shfl_xor(s, 2, 64);
                    s += __shfl_xor(s, 4, 64);
                    s += __shfl_xor(s, 8, 64);
                    const float q = e / s;
                    const int pos = pt*16 + hi*4 + r;
                    const int sidx = (pos*CH + qc) ^ ((pos & 7) << 3);
                    qlds[sidx] = (ushort)f2b(q);
                }
            }
        }
        __syncthreads();                                   // B2

        // --- stage C: D[c][pos] = Meff · q ---
        f32x4 d2[2][4];
        #pragma unroll
        for (int ct = 0; ct < 2; ++ct)
            #pragma unroll
            for (int pt = 0; pt < 4; ++pt) d2[ct][pt] = zero4;
        #pragma unroll
        for (int ks = 0; ks < 4; ++ks) {
            #pragma unroll
            for (int pt = 0; pt < 4; ++pt) {
                const int pos  = pt*16 + lo;
                const int sidx = (pos*CH + ks*32 + hi*8) ^ ((pos & 7) << 3);
                const bf16x8 qf = *(const bf16x8*)&qlds[sidx];
                #pragma unroll
                for (int ct = 0; ct < 2; ++ct)
                    d2[ct][pt] = __builtin_amdgcn_mfma_f32_16x16x32_bf16(mf[ct][ks], qf, d2[ct][pt], 0, 0, 0);
            }
        }

        // --- stage D: transpose d2 -> ylds [c][pos] (bf16, swizzled) ---
        #pragma unroll
        for (int ct = 0; ct < 2; ++ct)
            #pragma unroll
            for (int pt = 0; pt < 4; ++pt) {
                #pragma unroll
                for (int r = 0; r < 4; ++r) {
                    const int c = 32*w + ct*16 + hi*4 + r;
                    const int e = c*64 + ((pt*16 + lo) ^ ((c & 7) << 3));
                    ylds[e] = (ushort)f2b(d2[ct][pt][r]);
                }
            }
        __syncthreads();                                   // B3

        // --- epilogue: float4 residual + store ---
        #pragma unroll
        for (int i = 0; i < 8; ++i) {
            const int c = pc + 16*i;
            const size_t g = (size_t)c * NPIX + p0 + pL * 4;
            const float4 x4 = *(const float4*)(xb + g);
            const ushort4 y4 = *(const ushort4*)&ylds[c*64 + 4*(pL ^ ((c & 7) << 1))];
            float4 o;
            o.x = b2f(y4.x) + brv2[i] + x4.x;
            o.y = b2f(y4.y) + brv2[i] + x4.y;
            o.z = b2f(y4.z) + brv2[i] + x4.z;
            o.w = b2f(y4.w) + brv2[i] + x4.w;
            *(float4*)(outb + g) = o;
        }
    }
}

extern "C" void kernel_launch(void* const* d_in, const int* in_sizes, int n_in,
                              void* d_out, int out_size, void* d_ws, size_t ws_size,
                              hipStream_t stream)
{
    const float* x  = (const float*)d_in[0];
    const float* Wk = (const float*)d_in[1];
    const float* bk = (const float*)d_in[2];
    const float* Wq = (const float*)d_in[3];
    const float* bq = (const float*)d_in[4];
    const float* Wv = (const float*)d_in[5];
    const float* bv = (const float*)d_in[6];
    const float* Wr = (const float*)d_in[7];
    const float* br = (const float*)d_in[8];
    float* out = (float*)d_out;

    float*  Sp    = (float*)d_ws;                  // 16*64*2048 = 2,097,152 f
    float*  Zp    = Sp + (size_t)16*64*2048;       // 16*64*128  = 131,072 f
    float*  Sg    = Zp + (size_t)16*64*128;        // 32768 f
    float*  Zg    = Sg + 32768;                    // 2048 f
    ushort* Meffh = (ushort*)(Zg + 2048);          // 262144 ushort

    k1_context<<<dim3(BATCH * 64), dim3(256), 0, stream>>>(x, Wk, bk, Wv, bv, Sp, Zp);
    k1b_reduce<<<dim3(9, BATCH),   dim3(256), 0, stream>>>(Sp, Zp, Sg, Zg);
    k15_meff  <<<dim3(BATCH * 64), dim3(256), 0, stream>>>(Sg, Zg, Wr, Meffh);
    k2_out    <<<dim3(BATCH * 64), dim3(256), 0, stream>>>(x, Wq, bq, Meffh, br, out);
}

// Round 5
// 372.752 us; speedup vs baseline: 1.4471x; 1.1701x over previous
//
#include <hip/hip_runtime.h>
#include <hip/hip_bf16.h>

#define BATCH 16
#define CH    128
#define NPIX  16384
#define NHEAD 8

typedef __attribute__((ext_vector_type(8))) short bf16x8;
typedef __attribute__((ext_vector_type(4))) float f32x4;

__device__ __forceinline__ short f2b(float f) {
    union { float f; unsigned u; } v; v.f = f;
    unsigned r = v.u + 0x7fffu + ((v.u >> 16) & 1u);   // RNE
    return (short)(r >> 16);
}
__device__ __forceinline__ float b2f(ushort u) {
    union { unsigned u; float f; } v; v.u = ((unsigned)u) << 16; return v.f;
}

// x tile swizzle: LDS [pos][ch] bf16 (validated R1/R3/R4).
__device__ __forceinline__ int xswz(int p, int c) {
    const int v = ((p >> 2) & 15) ^ ((p & 3) << 2);
    return (p * CH + c) ^ (v << 3);
}

// ---------------------------------------------------------------------------
// k1: K/V GEMM + exp + context partials. grid 16*128 (2 subs of 64 pos),
// double-buffered LDS (2x16KB), 2 barriers/block, no atomics.
// ---------------------------------------------------------------------------
__global__ __launch_bounds__(256)
void k1_context(const float* __restrict__ x,
                const float* __restrict__ Wk, const float* __restrict__ bk,
                const float* __restrict__ Wv, const float* __restrict__ bv,
                float* __restrict__ Sp, float* __restrict__ Zp)
{
    __shared__ __align__(16) ushort xlds[2][64 * CH];   // 32 KB

    const int tid  = threadIdx.x;
    const int w    = tid >> 6;
    const int lane = tid & 63;
    const int lo   = lane & 15;
    const int hi   = lane >> 4;

    const int b     = blockIdx.x >> 7;
    const int chunk = blockIdx.x & 127;
    const float* xb = x + (size_t)b * CH * NPIX;

    const int pc = tid >> 4;        // staging channel base 0..15
    const int pL = tid & 15;        // staging float4 column

    // issue sub-0 staging loads
    float4 pf[8];
    {
        const int p0 = chunk * 128;
        #pragma unroll
        for (int i = 0; i < 8; ++i)
            pf[i] = *(const float4*)(xb + (size_t)(pc + 16*i) * NPIX + p0 + pL * 4);
    }

    // weight fragments (overlap with staging loads in flight)
    bf16x8 wkf[2][4], wvf[2][4];
    #pragma unroll
    for (int ct = 0; ct < 2; ++ct) {
        const int row = 32*w + ct*16 + lo;
        #pragma unroll
        for (int ks = 0; ks < 4; ++ks) {
            const int c0 = ks*32 + hi*8;
            const float4 k0 = *(const float4*)(Wk + row*CH + c0);
            const float4 k1 = *(const float4*)(Wk + row*CH + c0 + 4);
            const float4 v0 = *(const float4*)(Wv + row*CH + c0);
            const float4 v1 = *(const float4*)(Wv + row*CH + c0 + 4);
            bf16x8 fk, fv;
            fk[0]=f2b(k0.x); fk[1]=f2b(k0.y); fk[2]=f2b(k0.z); fk[3]=f2b(k0.w);
            fk[4]=f2b(k1.x); fk[5]=f2b(k1.y); fk[6]=f2b(k1.z); fk[7]=f2b(k1.w);
            fv[0]=f2b(v0.x); fv[1]=f2b(v0.y); fv[2]=f2b(v0.z); fv[3]=f2b(v0.w);
            fv[4]=f2b(v1.x); fv[5]=f2b(v1.y); fv[6]=f2b(v1.z); fv[7]=f2b(v1.w);
            wkf[ct][ks] = fk; wvf[ct][ks] = fv;
        }
    }
    float bkv[2], bvv[2];
    #pragma unroll
    for (int ct = 0; ct < 2; ++ct) {
        bkv[ct] = bk[32*w + ct*16 + lo];
        bvv[ct] = bv[32*w + ct*16 + lo];
    }

    const f32x4 zero4 = {0.f, 0.f, 0.f, 0.f};
    f32x4 sacc[2] = {zero4, zero4};
    float zacc[2] = {0.f, 0.f};

    #pragma unroll
    for (int sub = 0; sub < 2; ++sub) {
        ushort* buf = &xlds[sub][0];
        if (sub == 0) {
            // commit sub-0 regs -> buf0
            #pragma unroll
            for (int i = 0; i < 8; ++i) {
                const int c = pc + 16*i;
                #pragma unroll
                for (int kk = 0; kk < 4; ++kk)
                    buf[xswz(pL*4 + kk, c)] = (ushort)f2b(((const float*)&pf[i])[kk]);
            }
        }
        __syncthreads();                               // buf[sub] ready

        if (sub == 0) {                                // issue sub-1 loads
            const int pn = chunk*128 + 64;
            #pragma unroll
            for (int i = 0; i < 8; ++i)
                pf[i] = *(const float4*)(xb + (size_t)(pc + 16*i) * NPIX + pn + pL * 4);
        }

        #pragma unroll
        for (int ct = 0; ct < 2; ++ct) {
            f32x4 dk_[4], dv_[4];
            #pragma unroll
            for (int pt = 0; pt < 4; ++pt) { dk_[pt] = zero4; dv_[pt] = zero4; }
            #pragma unroll
            for (int ks = 0; ks < 4; ++ks) {
                #pragma unroll
                for (int pt = 0; pt < 4; ++pt) {
                    const bf16x8 xa = *(const bf16x8*)&buf[xswz(pt*16 + lo, ks*32 + hi*8)];
                    dk_[pt] = __builtin_amdgcn_mfma_f32_16x16x32_bf16(xa, wkf[ct][ks], dk_[pt], 0, 0, 0);
                    dv_[pt] = __builtin_amdgcn_mfma_f32_16x16x32_bf16(xa, wvf[ct][ks], dv_[pt], 0, 0, 0);
                }
            }
            bf16x8 ef[2], vf[2];
            #pragma unroll
            for (int pt = 0; pt < 4; ++pt) {
                #pragma unroll
                for (int r = 0; r < 4; ++r) {
                    float e = __expf(dk_[pt][r] + bkv[ct]);
                    zacc[ct] += e;
                    ef[pt >> 1][(pt & 1)*4 + r] = f2b(e);
                    vf[pt >> 1][(pt & 1)*4 + r] = f2b(dv_[pt][r] + bvv[ct]);
                }
            }
            #pragma unroll
            for (int kg = 0; kg < 2; ++kg)
                sacc[ct] = __builtin_amdgcn_mfma_f32_16x16x32_bf16(ef[kg], vf[kg], sacc[ct], 0, 0, 0);
        }

        if (sub == 0) {
            // commit sub-1 regs -> buf1 (readers gated by next barrier)
            ushort* nb = &xlds[1][0];
            #pragma unroll
            for (int i = 0; i < 8; ++i) {
                const int c = pc + 16*i;
                #pragma unroll
                for (int kk = 0; kk < 4; ++kk)
                    nb[xswz(pL*4 + kk, c)] = (ushort)f2b(((const float*)&pf[i])[kk]);
            }
        }
    }

    // per-chunk partials, plain coalesced stores
    float* sp = Sp + (size_t)(b*128 + chunk) * 2048;
    #pragma unroll
    for (int ct = 0; ct < 2; ++ct)
        #pragma unroll
        for (int r = 0; r < 4; ++r)
            sp[(2*w + ct)*256 + (hi*4 + r)*16 + lo] = sacc[ct][r];

    #pragma unroll
    for (int ct = 0; ct < 2; ++ct) {
        float z = zacc[ct];
        z += __shfl_xor(z, 16, 64);
        z += __shfl_xor(z, 32, 64);
        if (hi == 0)
            Zp[(size_t)(b*128 + chunk) * 128 + 32*w + ct*16 + lo] = z;
    }
}

// ---------------------------------------------------------------------------
// k1b: reduce 128 per-chunk partials. grid (9,16), 256 thr.
// ---------------------------------------------------------------------------
__global__ __launch_bounds__(256)
void k1b_reduce(const float* __restrict__ Sp, const float* __restrict__ Zp,
                float* __restrict__ Sg, float* __restrict__ Zg)
{
    const int b = blockIdx.y;
    const int j = blockIdx.x * 256 + threadIdx.x;
    if (j < 2048) {
        const float* p = Sp + (size_t)b * 128 * 2048 + j;
        float a = 0.f;
        #pragma unroll 8
        for (int c = 0; c < 128; ++c) a += p[(size_t)c * 2048];
        Sg[b*2048 + j] = a;
    } else if (j < 2176) {
        const int k = j - 2048;
        const float* p = Zp + (size_t)b * 128 * 128 + k;
        float a = 0.f;
        #pragma unroll 8
        for (int c = 0; c < 128; ++c) a += p[(size_t)c * 128];
        Zg[b*128 + k] = a;
    }
}

// ---------------------------------------------------------------------------
// k15: Meff (bf16) = (Wr · S) / Z.  grid 16*64, 256 thr.
// ---------------------------------------------------------------------------
__global__ __launch_bounds__(256)
void k15_meff(const float* __restrict__ Sg, const float* __restrict__ Zg,
              const float* __restrict__ Wr, ushort* __restrict__ Meffh)
{
    const int b   = blockIdx.x >> 6;
    const int idx = (blockIdx.x & 63) * 256 + threadIdx.x;
    const int c   = idx >> 7;
    const int kcg = idx & 127;
    const int h   = kcg >> 4;
    const int kc  = kcg & 15;
    const float* sp = Sg + (size_t)b*2048 + h*256 + kc*16;
    const float* wr = Wr + (size_t)c * CH + h*16;
    float acc = 0.f;
    #pragma unroll
    for (int v4i = 0; v4i < 4; ++v4i) {
        const float4 sv = *(const float4*)(sp + v4i*4);
        const float4 wv = *(const float4*)(wr + v4i*4);
        acc += sv.x*wv.x + sv.y*wv.y + sv.z*wv.z + sv.w*wv.w;
    }
    Meffh[((size_t)b*CH + c)*CH + kcg] = (ushort)f2b(acc / Zg[b*128 + kcg]);
}

// ---------------------------------------------------------------------------
// k2: Q GEMM -> per-head softmax -> qlds -> Meff GEMM -> direct stores with
// residual from xlds. grid 16*128 (2 subs of 64 pos), 32KB LDS.
// ---------------------------------------------------------------------------
__global__ __launch_bounds__(256)
void k2_out(const float* __restrict__ x,
            const float* __restrict__ Wq, const float* __restrict__ bq,
            const ushort* __restrict__ Meffh, const float* __restrict__ br,
            float* __restrict__ out)
{
    __shared__ __align__(16) ushort xlds[64 * CH];   // 16 KB
    __shared__ __align__(16) ushort qlds[64 * CH];   // 16 KB

    const int tid  = threadIdx.x;
    const int w    = tid >> 6;
    const int lane = tid & 63;
    const int lo   = lane & 15;
    const int hi   = lane >> 4;

    const int b     = blockIdx.x >> 7;
    const int chunk = blockIdx.x & 127;
    const size_t xbase = (size_t)b * CH * NPIX;
    const float* xb = x + xbase;
    float* outb = out + xbase;

    const int pc = tid >> 4;
    const int pL = tid & 15;

    // issue sub-0 staging loads
    float4 pf[8];
    {
        const int p0 = chunk * 128;
        #pragma unroll
        for (int i = 0; i < 8; ++i)
            pf[i] = *(const float4*)(xb + (size_t)(pc + 16*i) * NPIX + p0 + pL * 4);
    }

    // weights: Wq fp32->bf16; Meff already bf16
    bf16x8 wqf[2][4], mf[2][4];
    #pragma unroll
    for (int ct = 0; ct < 2; ++ct) {
        const int row = 32*w + ct*16 + lo;
        #pragma unroll
        for (int ks = 0; ks < 4; ++ks) {
            const int c0 = ks*32 + hi*8;
            const float4 q0 = *(const float4*)(Wq + row*CH + c0);
            const float4 q1 = *(const float4*)(Wq + row*CH + c0 + 4);
            bf16x8 fq;
            fq[0]=f2b(q0.x); fq[1]=f2b(q0.y); fq[2]=f2b(q0.z); fq[3]=f2b(q0.w);
            fq[4]=f2b(q1.x); fq[5]=f2b(q1.y); fq[6]=f2b(q1.z); fq[7]=f2b(q1.w);
            wqf[ct][ks] = fq;
            mf[ct][ks] = *(const bf16x8*)(Meffh + ((size_t)b*CH + row)*CH + c0);
        }
    }
    float bqv[2];
    #pragma unroll
    for (int ct = 0; ct < 2; ++ct) bqv[ct] = bq[32*w + ct*16 + lo];
    float brv[2][4];
    #pragma unroll
    for (int ct = 0; ct < 2; ++ct)
        #pragma unroll
        for (int r = 0; r < 4; ++r) brv[ct][r] = br[32*w + ct*16 + hi*4 + r];

    const f32x4 zero4 = {0.f, 0.f, 0.f, 0.f};

    #pragma unroll
    for (int sub = 0; sub < 2; ++sub) {
        const int p0 = chunk*128 + sub*64;

        // commit prefetched regs -> xlds
        #pragma unroll
        for (int i = 0; i < 8; ++i) {
            const int c = pc + 16*i;
            #pragma unroll
            for (int kk = 0; kk < 4; ++kk)
                xlds[xswz(pL*4 + kk, c)] = (ushort)f2b(((const float*)&pf[i])[kk]);
        }
        __syncthreads();                               // B1: xlds ready

        if (sub == 0) {                                // issue sub-1 loads
            const int pn = chunk*128 + 64;
            #pragma unroll
            for (int i = 0; i < 8; ++i)
                pf[i] = *(const float4*)(xb + (size_t)(pc + 16*i) * NPIX + pn + pL * 4);
        }

        // --- stage A: queries D[pos][qc] ---
        f32x4 dq[2][4];
        #pragma unroll
        for (int ct = 0; ct < 2; ++ct)
            #pragma unroll
            for (int pt = 0; pt < 4; ++pt) dq[ct][pt] = zero4;
        #pragma unroll
        for (int ks = 0; ks < 4; ++ks) {
            #pragma unroll
            for (int pt = 0; pt < 4; ++pt) {
                const bf16x8 xa = *(const bf16x8*)&xlds[xswz(pt*16 + lo, ks*32 + hi*8)];
                #pragma unroll
                for (int ct = 0; ct < 2; ++ct)
                    dq[ct][pt] = __builtin_amdgcn_mfma_f32_16x16x32_bf16(xa, wqf[ct][ks], dq[ct][pt], 0, 0, 0);
            }
        }

        // --- stage B: per-head softmax (16 lanes), write qlds ---
        #pragma unroll
        for (int ct = 0; ct < 2; ++ct) {
            const int qc = 32*w + ct*16 + lo;
            #pragma unroll
            for (int pt = 0; pt < 4; ++pt) {
                #pragma unroll
                for (int r = 0; r < 4; ++r) {
                    const float e = __expf(dq[ct][pt][r] + bqv[ct]);
                    float s = e;
                    s += __shfl_xor(s, 1, 64);
                    s += __shfl_xor(s, 2, 64);
                    s += __shfl_xor(s, 4, 64);
                    s += __shfl_xor(s, 8, 64);
                    const float q = e * __builtin_amdgcn_rcpf(s);
                    const int pos = pt*16 + hi*4 + r;
                    const int sidx = (pos*CH + qc) ^ ((pos & 7) << 3);
                    qlds[sidx] = (ushort)f2b(q);
                }
            }
        }
        __syncthreads();                               // B2: qlds ready

        // --- stage C: D[c][pos] = Meff · q ---
        f32x4 d2[2][4];
        #pragma unroll
        for (int ct = 0; ct < 2; ++ct)
            #pragma unroll
            for (int pt = 0; pt < 4; ++pt) d2[ct][pt] = zero4;
        #pragma unroll
        for (int ks = 0; ks < 4; ++ks) {
            #pragma unroll
            for (int pt = 0; pt < 4; ++pt) {
                const int pos  = pt*16 + lo;
                const int sidx = (pos*CH + ks*32 + hi*8) ^ ((pos & 7) << 3);
                const bf16x8 qf = *(const bf16x8*)&qlds[sidx];
                #pragma unroll
                for (int ct = 0; ct < 2; ++ct)
                    d2[ct][pt] = __builtin_amdgcn_mfma_f32_16x16x32_bf16(mf[ct][ks], qf, d2[ct][pt], 0, 0, 0);
            }
        }

        // --- epilogue: + br + x (residual from xlds), direct stores ---
        #pragma unroll
        for (int ct = 0; ct < 2; ++ct)
            #pragma unroll
            for (int pt = 0; pt < 4; ++pt) {
                const int n   = p0 + pt*16 + lo;
                const int pos = pt*16 + lo;
                #pragma unroll
                for (int r = 0; r < 4; ++r) {
                    const int cc = 32*w + ct*16 + hi*4 + r;
                    outb[(size_t)cc * NPIX + n] =
                        d2[ct][pt][r] + brv[ct][r] + b2f(xlds[xswz(pos, cc)]);
                }
            }

        if (sub == 0) __syncthreads();                 // B3: tile reads done
    }
}

extern "C" void kernel_launch(void* const* d_in, const int* in_sizes, int n_in,
                              void* d_out, int out_size, void* d_ws, size_t ws_size,
                              hipStream_t stream)
{
    const float* x  = (const float*)d_in[0];
    const float* Wk = (const float*)d_in[1];
    const float* bk = (const float*)d_in[2];
    const float* Wq = (const float*)d_in[3];
    const float* bq = (const float*)d_in[4];
    const float* Wv = (const float*)d_in[5];
    const float* bv = (const float*)d_in[6];
    const float* Wr = (const float*)d_in[7];
    const float* br = (const float*)d_in[8];
    float* out = (float*)d_out;

    float*  Sp    = (float*)d_ws;                   // 16*128*2048 = 4,194,304 f
    float*  Zp    = Sp + (size_t)16*128*2048;       // 16*128*128  = 262,144 f
    float*  Sg    = Zp + (size_t)16*128*128;        // 32768 f
    float*  Zg    = Sg + 32768;                     // 2048 f
    ushort* Meffh = (ushort*)(Zg + 2048);           // 262144 ushort

    k1_context<<<dim3(BATCH * 128), dim3(256), 0, stream>>>(x, Wk, bk, Wv, bv, Sp, Zp);
    k1b_reduce<<<dim3(9, BATCH),    dim3(256), 0, stream>>>(Sp, Zp, Sg, Zg);
    k15_meff  <<<dim3(BATCH * 64),  dim3(256), 0, stream>>>(Sg, Zg, Wr, Meffh);
    k2_out    <<<dim3(BATCH * 128), dim3(256), 0, stream>>>(x, Wq, bq, Meffh, br, out);
}